// Round 3
// baseline (709.091 us; speedup 1.0000x reference)
//
#include <hip/hip_runtime.h>

#define NB 512
#define NL 1024
#define NT 48
#define CH 8
#define NCH (NL/CH)
#define LN2F 0.69314718055994531f

typedef float v2f __attribute__((ext_vector_type(2)));

__device__ __forceinline__ void pkfma(v2f& acc, v2f a, v2f b) {
    asm("v_pk_fma_f32 %0, %1, %2, %0" : "+v"(acc) : "v"(a), "v"(b));
}

// Process one chunk of CH steps for both chains. Branchless per-step body:
// single basic block so the compiler can interleave chain0/chain1 freely.
#define RUN_CHUNK(CC, W0,W1,T0,T1,M0,M1, N0,N1,U0,U1,P0,P1)                     \
do {                                                                            \
    const int cn_ = (CC) + 1;                                                   \
    if (cn_ < NCH) {                                                            \
        _Pragma("unroll")                                                       \
        for (int k = 0; k < CH; ++k) {                                          \
            const int l = cn_*CH + k;                                           \
            N0[k] = fb0[l*NT + jl]; U0[k] = tgp0[l]; P0[k] = mkp0[l];           \
            N1[k] = fb1[l*NT + jl]; U1[k] = tgp1[l]; P1[k] = mkp1[l];           \
        }                                                                       \
    }                                                                           \
    /* prep: gold scores + emit->exp(emit), all off the serial path */          \
    _Pragma("unroll")                                                           \
    for (int k = 0; k < CH; ++k) {                                              \
        const float em0 = W0[k]; const int tg0 = T0[k]; const int mm0 = M0[k];  \
        const float em1 = W1[k]; const int tg1 = T1[k]; const int mm1 = M1[k];  \
        const int pv0 = (k == 0) ? tp0 : T0[k-1];                               \
        const int pv1 = (k == 0) ? tp1 : T1[k-1];                               \
        const float tr0 = trans[pv0*NT + tg0];                                  \
        const float tr1 = trans[pv1*NT + tg1];                                  \
        const bool fsp_ = ((CC) == 0) && (k == 0);                              \
        gT0 += (mm0 > 0 && !fsp_) ? tr0 : 0.f;                                  \
        gT1 += (mm1 > 0 && !fsp_) ? tr1 : 0.f;                                  \
        gE0 += (mm0 > 0 && lane == tg0) ? em0 : 0.f;                            \
        gE1 += (mm1 > 0 && lane == tg1) ? em1 : 0.f;                            \
        W0[k] = __expf(em0);                                                    \
        W1[k] = __expf(em1);                                                    \
    }                                                                           \
    tp0 = T0[CH-1]; tp1 = T1[CH-1];                                             \
    /* serial recurrence: V' = (ET^T V) * W, exponent-stripped every 2 steps */ \
    _Pragma("unroll")                                                           \
    for (int k = 0; k < CH; ++k) {                                              \
        eBuf0[lane] = V0;                                                       \
        eBuf1[lane] = V1;                                                       \
        asm volatile("" ::: "memory"); /* DS in-order per wave; compile barrier */ \
        const float4* e40 = reinterpret_cast<const float4*>(eBuf0);             \
        const float4* e41 = reinterpret_cast<const float4*>(eBuf1);             \
        v2f a00={0.f,0.f}, a01={0.f,0.f}, a02={0.f,0.f}, a03={0.f,0.f};         \
        v2f a10={0.f,0.f}, a11={0.f,0.f}, a12={0.f,0.f}, a13={0.f,0.f};         \
        _Pragma("unroll")                                                       \
        for (int q = 0; q < 12; ++q) {                                          \
            const float4 ev0 = e40[q];                                          \
            const float4 ev1 = e41[q];                                          \
            v2f l0; l0.x = ev0.x; l0.y = ev0.y;                                 \
            v2f h0; h0.x = ev0.z; h0.y = ev0.w;                                 \
            v2f l1; l1.x = ev1.x; l1.y = ev1.y;                                 \
            v2f h1; h1.x = ev1.z; h1.y = ev1.w;                                 \
            if (q & 1) {                                                        \
                pkfma(a02, l0, et2[2*q+0]); pkfma(a03, h0, et2[2*q+1]);         \
                pkfma(a12, l1, et2[2*q+0]); pkfma(a13, h1, et2[2*q+1]);         \
            } else {                                                            \
                pkfma(a00, l0, et2[2*q+0]); pkfma(a01, h0, et2[2*q+1]);         \
                pkfma(a10, l1, et2[2*q+0]); pkfma(a11, h1, et2[2*q+1]);         \
            }                                                                   \
        }                                                                       \
        const v2f s0 = (a00 + a02) + (a01 + a03);                               \
        const v2f s1 = (a10 + a12) + (a11 + a13);                               \
        const float d0 = s0.x + s0.y;                                           \
        const float d1 = s1.x + s1.y;                                           \
        const bool fs_ = ((CC) == 0) && (k == 0);                               \
        V0 = fs_ ? W0[0] : ((M0[k] > 0) ? d0 * W0[k] : V0);                     \
        V1 = fs_ ? W1[0] : ((M1[k] > 0) ? d1 * W1[k] : V1);                     \
        if (k & 1) {                                                            \
            const int bb0 = __builtin_amdgcn_readfirstlane(__float_as_int(V0)); \
            const int eb0 = ((bb0 >> 23) & 255) - 127;                          \
            V0 *= __int_as_float((127 - eb0) << 23);                            \
            es0 += eb0;                                                         \
            const int bb1 = __builtin_amdgcn_readfirstlane(__float_as_int(V1)); \
            const int eb1 = ((bb1 >> 23) & 255) - 127;                          \
            V1 *= __int_as_float((127 - eb1) << 23);                            \
            es1 += eb1;                                                         \
        }                                                                       \
    }                                                                           \
} while (0)

__global__ void __launch_bounds__(64) crf_nll_kernel(
    const float* __restrict__ feats,
    const float* __restrict__ trans,
    const int* __restrict__ tags,
    const int* __restrict__ mask,
    float* __restrict__ out)
{
    const int lane = (int)threadIdx.x;
    const int jl = lane < NT ? lane : NT - 1;
    const int b0 = (int)blockIdx.x * 2;

    __shared__ __align__(16) float eBuf0[64];
    __shared__ __align__(16) float eBuf1[64];

    // et2[q] = { exp(trans[2q][j]), exp(trans[2q+1][j]) } for this lane's tag j
    v2f et2[NT/2];
    #pragma unroll
    for (int q = 0; q < NT/2; ++q) {
        v2f e;
        e.x = __expf(trans[(2*q+0)*NT + jl]);
        e.y = __expf(trans[(2*q+1)*NT + jl]);
        et2[q] = e;
    }

    const float* fb0 = feats + (size_t)(b0+0)*NL*NT;
    const float* fb1 = feats + (size_t)(b0+1)*NL*NT;
    const int* tgp0 = tags + (size_t)(b0+0)*NL;
    const int* tgp1 = tags + (size_t)(b0+1)*NL;
    const int* mkp0 = mask + (size_t)(b0+0)*NL;
    const int* mkp1 = mask + (size_t)(b0+1)*NL;

    // exp-domain state: alpha[j] = es*ln2 + log(V[j])
    float V0 = 1.f, V1 = 1.f;
    int   es0 = 0, es1 = 0;
    float gT0 = 0.f, gT1 = 0.f, gE0 = 0.f, gE1 = 0.f;
    int   tp0 = 0, tp1 = 0;

    float wA0[CH], wA1[CH], wB0[CH], wB1[CH];
    int   tA0[CH], tA1[CH], tB0[CH], tB1[CH];
    int   mA0[CH], mA1[CH], mB0[CH], mB1[CH];

    #pragma unroll
    for (int k = 0; k < CH; ++k) {
        wA0[k] = fb0[k*NT + jl]; tA0[k] = tgp0[k]; mA0[k] = mkp0[k];
        wA1[k] = fb1[k*NT + jl]; tA1[k] = tgp1[k]; mA1[k] = mkp1[k];
    }

    for (int cc = 0; cc < NCH; cc += 2) {
        RUN_CHUNK(cc,   wA0,wA1,tA0,tA1,mA0,mA1, wB0,wB1,tB0,tB1,mB0,mB1);
        RUN_CHUNK(cc+1, wB0,wB1,tB0,tB1,mB0,mB1, wA0,wA1,tA0,tA1,mA0,mA1);
    }

    // logZ = es*ln2 + log(sum_j V[j]); nll = logZ - gold
    float v0 = (lane < NT) ? V0 : 0.f;
    float v1 = (lane < NT) ? V1 : 0.f;
    float g0 = gE0, g1 = gE1;
    #pragma unroll
    for (int o = 32; o > 0; o >>= 1) {
        v0 += __shfl_xor(v0, o, 64);
        v1 += __shfl_xor(v1, o, 64);
        g0 += __shfl_xor(g0, o, 64);
        g1 += __shfl_xor(g1, o, 64);
    }
    if (lane == 0) {
        out[b0+0] = (float)es0 * LN2F + __logf(v0) - gT0 - g0;
        out[b0+1] = (float)es1 * LN2F + __logf(v1) - gT1 - g1;
    }
}

extern "C" void kernel_launch(void* const* d_in, const int* in_sizes, int n_in,
                              void* d_out, int out_size, void* d_ws, size_t ws_size,
                              hipStream_t stream) {
    const float* feats = (const float*)d_in[0];
    const float* trans = (const float*)d_in[1];
    const int*   tags  = (const int*)d_in[2];
    const int*   mask  = (const int*)d_in[3];
    float* out = (float*)d_out;

    crf_nll_kernel<<<dim3(NB/2), dim3(64), 0, stream>>>(feats, trans, tags, mask, out);
}

// Round 4
// 398.771 us; speedup vs baseline: 1.7782x; 1.7782x over previous
//
#include <hip/hip_runtime.h>
#include <hip/hip_bf16.h>

#define NB 512
#define NL 1024
#define NT 48
#define CH 8
#define NCH (NL/CH)
#define LN2F 0.69314718055994531f

typedef float f32x4 __attribute__((ext_vector_type(4)));
typedef short b16x4 __attribute__((ext_vector_type(4)));

__device__ __forceinline__ f32x4 MFMA16(b16x4 a, b16x4 b, f32x4 c) {
#if __has_builtin(__builtin_amdgcn_mfma_f32_16x16x16bf16_1k)
    return __builtin_amdgcn_mfma_f32_16x16x16bf16_1k(a, b, c, 0, 0, 0);
#elif __has_builtin(__builtin_amdgcn_mfma_f32_16x16x16_bf16)
    return __builtin_amdgcn_mfma_f32_16x16x16_bf16(a, b, c, 0, 0, 0);
#else
    asm("v_mfma_f32_16x16x16_bf16 %0, %1, %2, %0" : "+v"(c) : "v"(a), "v"(b));
    return c;
#endif
}

__device__ __forceinline__ unsigned pkbf16(float lo, float hi) {
    __hip_bfloat162 h = __float22bfloat162_rn(make_float2(lo, hi));
    unsigned u;
    __builtin_memcpy(&u, &h, 4);
    return u;
}

__device__ __forceinline__ b16x4 packV(f32x4 v) {
    union { b16x4 b; unsigned u[2]; } r;
    r.u[0] = pkbf16(v.x, v.y);
    r.u[1] = pkbf16(v.z, v.w);
    return r.b;
}

// One recurrence step. kk, F are compile-time literals.
#define STEP(kk, F, cc) do {                                                    \
    f32x4 W0, W1, W2;                                                           \
    W0.x = __expf(EB[0][kk].x); W0.y = __expf(EB[0][kk].y);                     \
    W0.z = __expf(EB[0][kk].z); W0.w = __expf(EB[0][kk].w);                     \
    W1.x = __expf(EB[1][kk].x); W1.y = __expf(EB[1][kk].y);                     \
    W1.z = __expf(EB[1][kk].z); W1.w = __expf(EB[1][kk].w);                     \
    W2.x = __expf(EB[2][kk].x); W2.y = __expf(EB[2][kk].y);                     \
    W2.z = __expf(EB[2][kk].z); W2.w = __expf(EB[2][kk].w);                     \
    { /* prefetch next chunk, same slot (clamped at tail: harmless reload) */   \
        const int tn = ((((cc)+1) < NCH) ? ((cc)+1) : (cc)) * CH + (kk);        \
        EB[0][kk] = *(const f32x4*)(fb + (size_t)tn*NT +  0 + g*4);             \
        EB[1][kk] = *(const f32x4*)(fb + (size_t)tn*NT + 16 + g*4);             \
        EB[2][kk] = *(const f32x4*)(fb + (size_t)tn*NT + 32 + g*4);             \
    }                                                                           \
    if ((F) && (kk) == 0) {                                                     \
        V[0] = W0; V[1] = W1; V[2] = W2;   /* alpha0 = f[0] */                  \
    } else {                                                                    \
        const f32x4 z = {0.f, 0.f, 0.f, 0.f};                                   \
        f32x4 d0 = MFMA16(A[0][0], Bf[0], z);                                   \
        f32x4 d1 = MFMA16(A[1][0], Bf[0], z);                                   \
        f32x4 d2 = MFMA16(A[2][0], Bf[0], z);                                   \
        d0 = MFMA16(A[0][1], Bf[1], d0);                                        \
        d1 = MFMA16(A[1][1], Bf[1], d1);                                        \
        d2 = MFMA16(A[2][1], Bf[1], d2);                                        \
        d0 = MFMA16(A[0][2], Bf[2], d0);                                        \
        d1 = MFMA16(A[1][2], Bf[2], d1);                                        \
        d2 = MFMA16(A[2][2], Bf[2], d2);                                        \
        const bool mk_ = mkc[kk] > 0;                                           \
        V[0] = mk_ ? d0 * W0 : V[0];                                            \
        V[1] = mk_ ? d1 * W1 : V[1];                                            \
        V[2] = mk_ ? d2 * W2 : V[2];                                            \
    }                                                                           \
    if (((kk) & 3) == 3) { /* renorm: strip max binary exponent (per chain) */  \
        float mx = fmaxf(fmaxf(fmaxf(V[0].x, V[0].y), fmaxf(V[0].z, V[0].w)),   \
                   fmaxf(fmaxf(fmaxf(V[1].x, V[1].y), fmaxf(V[1].z, V[1].w)),   \
                         fmaxf(fmaxf(V[2].x, V[2].y), fmaxf(V[2].z, V[2].w)))); \
        mx = fmaxf(mx, __shfl_xor(mx, 16, 64));                                 \
        mx = fmaxf(mx, __shfl_xor(mx, 32, 64));                                 \
        const int eb_ = (__float_as_int(mx) >> 23) & 255;                       \
        const float sc_ = __int_as_float((254 - eb_) << 23);                    \
        es += eb_ - 127;                                                        \
        V[0] *= sc_; V[1] *= sc_; V[2] *= sc_;                                  \
    }                                                                           \
    Bf[0] = packV(V[0]); Bf[1] = packV(V[1]); Bf[2] = packV(V[2]);              \
} while (0)

#define CHUNK(F, cc) do {                                                       \
    { /* prefetch next chunk's tags+mask */                                     \
        const int ccn = (((cc)+1) < NCH) ? ((cc)+1) : (cc);                     \
        int4 a_ = *(const int4*)(tgP + ccn*CH);                                 \
        int4 b_ = *(const int4*)(tgP + ccn*CH + 4);                             \
        tgn[0]=a_.x; tgn[1]=a_.y; tgn[2]=a_.z; tgn[3]=a_.w;                     \
        tgn[4]=b_.x; tgn[5]=b_.y; tgn[6]=b_.z; tgn[7]=b_.w;                     \
        int4 c_ = *(const int4*)(mkP + ccn*CH);                                 \
        int4 d_ = *(const int4*)(mkP + ccn*CH + 4);                             \
        mkn[0]=c_.x; mkn[1]=c_.y; mkn[2]=c_.z; mkn[3]=c_.w;                     \
        mkn[4]=d_.x; mkn[5]=d_.y; mkn[6]=d_.z; mkn[7]=d_.w;                     \
    }                                                                           \
    float gtr[CH], gem[CH];                                                     \
    if (lane < 16) { /* gold gathers for current chunk (consumed at end) */     \
        int pv_ = tp;                                                           \
        _Pragma("unroll")                                                       \
        for (int k = 0; k < CH; ++k) {                                          \
            const int cur_ = tgc[k];                                            \
            gtr[k] = trans[pv_*NT + cur_];                                      \
            gem[k] = fb[(size_t)((cc)*CH + k)*NT + cur_];                       \
            pv_ = cur_;                                                         \
        }                                                                       \
    }                                                                           \
    tp = tgc[CH-1];                                                             \
    STEP(0,F,cc); STEP(1,F,cc); STEP(2,F,cc); STEP(3,F,cc);                     \
    STEP(4,F,cc); STEP(5,F,cc); STEP(6,F,cc); STEP(7,F,cc);                     \
    if (lane < 16) {                                                            \
        _Pragma("unroll")                                                       \
        for (int k = 0; k < CH; ++k) {                                          \
            if (mkc[k] > 0) {                                                   \
                gE += gem[k];                                                   \
                if (!((F) && k == 0)) gT += gtr[k];                             \
            }                                                                   \
        }                                                                       \
    }                                                                           \
    _Pragma("unroll")                                                           \
    for (int k = 0; k < CH; ++k) { tgc[k] = tgn[k]; mkc[k] = mkn[k]; }          \
} while (0)

__global__ void __launch_bounds__(64, 1) crf_nll_kernel(
    const float* __restrict__ feats,
    const float* __restrict__ trans,
    const int* __restrict__ tags,
    const int* __restrict__ mask,
    float* __restrict__ out)
{
    const int lane = (int)threadIdx.x;
    const int m = lane & 15;     // chain within 16-batch group
    const int g = lane >> 4;     // row group
    const int b0 = (int)blockIdx.x * 16;

    // Static A fragments: A[jt][kc] holds exp(trans[i][j]) at
    // row j = jt*16 + m, k = i = kc*16 + g*4 + e  (e = 0..3)
    b16x4 A[3][3];
    #pragma unroll
    for (int jt = 0; jt < 3; ++jt) {
        #pragma unroll
        for (int kc = 0; kc < 3; ++kc) {
            const int j = jt*16 + m;
            const float e0 = __expf(trans[(kc*16 + g*4 + 0)*NT + j]);
            const float e1 = __expf(trans[(kc*16 + g*4 + 1)*NT + j]);
            const float e2 = __expf(trans[(kc*16 + g*4 + 2)*NT + j]);
            const float e3 = __expf(trans[(kc*16 + g*4 + 3)*NT + j]);
            union { b16x4 b; unsigned u[2]; } r;
            r.u[0] = pkbf16(e0, e1);
            r.u[1] = pkbf16(e2, e3);
            A[jt][kc] = r.b;
        }
    }

    const float* fb = feats + (size_t)(b0 + m) * NL * NT;  // this lane's chain
    const int* tgP = tags + (size_t)(b0 + m) * NL;
    const int* mkP = mask + (size_t)(b0 + m) * NL;

    // Emit prefetch buffer: EB[jt][k] = float4 at fb + t*NT + jt*16 + g*4
    f32x4 EB[3][CH];
    #pragma unroll
    for (int k = 0; k < CH; ++k) {
        #pragma unroll
        for (int jt = 0; jt < 3; ++jt)
            EB[jt][k] = *(const f32x4*)(fb + (size_t)k*NT + jt*16 + g*4);
    }

    int tgc[CH], mkc[CH], tgn[CH], mkn[CH];
    {
        int4 a_ = *(const int4*)(tgP);
        int4 b_ = *(const int4*)(tgP + 4);
        tgc[0]=a_.x; tgc[1]=a_.y; tgc[2]=a_.z; tgc[3]=a_.w;
        tgc[4]=b_.x; tgc[5]=b_.y; tgc[6]=b_.z; tgc[7]=b_.w;
        int4 c_ = *(const int4*)(mkP);
        int4 d_ = *(const int4*)(mkP + 4);
        mkc[0]=c_.x; mkc[1]=c_.y; mkc[2]=c_.z; mkc[3]=c_.w;
        mkc[4]=d_.x; mkc[5]=d_.y; mkc[6]=d_.z; mkc[7]=d_.w;
    }

    f32x4 V[3];          // exp-domain state, f32 (tags jt*16+g*4+r, chain m)
    b16x4 Bf[3];         // bf16-packed V = next step's B fragments
    int es = 0;          // stripped binary exponent (per chain, uniform in group)
    float gT = 0.f, gE = 0.f;
    int tp = 0;

    CHUNK(1, 0);
    for (int cc = 1; cc < NCH; ++cc) {
        CHUNK(0, cc);
    }

    // logZ = es*ln2 + log(sum_j V[j]) ; reduce across 4 partner lanes
    float s = ((V[0].x + V[0].y) + (V[0].z + V[0].w))
            + ((V[1].x + V[1].y) + (V[1].z + V[1].w))
            + ((V[2].x + V[2].y) + (V[2].z + V[2].w));
    s += __shfl_xor(s, 16, 64);
    s += __shfl_xor(s, 32, 64);

    const float res = (float)es * LN2F + __logf(s) - gT - gE;
    if (lane < 16) out[b0 + lane] = res;
}

extern "C" void kernel_launch(void* const* d_in, const int* in_sizes, int n_in,
                              void* d_out, int out_size, void* d_ws, size_t ws_size,
                              hipStream_t stream) {
    const float* feats = (const float*)d_in[0];
    const float* trans = (const float*)d_in[1];
    const int*   tags  = (const int*)d_in[2];
    const int*   mask  = (const int*)d_in[3];
    float* out = (float*)d_out;

    crf_nll_kernel<<<dim3(NB/16), dim3(64), 0, stream>>>(feats, trans, tags, mask, out);
}

// Round 8
// 383.925 us; speedup vs baseline: 1.8470x; 1.0387x over previous
//
#include <hip/hip_runtime.h>
#include <hip/hip_bf16.h>

#define NB 512
#define NL 1024
#define NT 48
#define NSEG 8
#define SEGLEN (NL/NSEG)   // 128
#define CH 8
#define NCH (NL/CH)
#define LN2F 0.69314718055994531f

typedef float f32x4 __attribute__((ext_vector_type(4)));
typedef short b16x4 __attribute__((ext_vector_type(4)));

static __device__ __forceinline__ f32x4 MFMA16(b16x4 a, b16x4 b, f32x4 c) {
#if __has_builtin(__builtin_amdgcn_mfma_f32_16x16x16bf16_1k)
    return __builtin_amdgcn_mfma_f32_16x16x16bf16_1k(a, b, c, 0, 0, 0);
#elif __has_builtin(__builtin_amdgcn_mfma_f32_16x16x16_bf16)
    return __builtin_amdgcn_mfma_f32_16x16x16_bf16(a, b, c, 0, 0, 0);
#else
    asm("v_mfma_f32_16x16x16_bf16 %0, %1, %2, %0" : "+v"(c) : "v"(a), "v"(b));
    return c;
#endif
}

static __device__ __forceinline__ unsigned pkbf16(float lo, float hi) {
    __hip_bfloat162 h = __float22bfloat162_rn(make_float2(lo, hi));
    unsigned u;
    __builtin_memcpy(&u, &h, 4);
    return u;
}

static __device__ __forceinline__ b16x4 packV(f32x4 v) {
    union { b16x4 b; unsigned u[2]; } r;
    r.u[0] = pkbf16(v.x, v.y);
    r.u[1] = pkbf16(v.z, v.w);
    return r.b;
}

static __device__ __forceinline__ float bf16lo(unsigned u) { return __uint_as_float(u << 16); }
static __device__ __forceinline__ float bf16hi(unsigned u) { return __uint_as_float(u & 0xFFFF0000u); }

static __device__ __forceinline__ float vmax4(f32x4 v) {
    return fmaxf(fmaxf(v.x, v.y), fmaxf(v.z, v.w));
}

// ---------------- Phase 1: per-(batch, segment) 48x48 product matrix ----------------
// Q_{t+1} = diag(w_t) * ET^T * Q_t  in exp domain, Q_0 = I.
// One wave per (b, s); Q lives entirely in registers as 9 bf16 MFMA B-fragments.
// D-layout (col=lane&15, row=(lane>>4)*4+reg) == B-layout (col, k) -> no data movement.
__global__ void __launch_bounds__(64) crf_phase1(
    const float* __restrict__ feats,
    const float* __restrict__ trans,
    const int* __restrict__ mask,
    unsigned short* __restrict__ qws,
    int* __restrict__ esws)
{
    const int lane = (int)threadIdx.x;
    const int m = lane & 15;
    const int g = lane >> 4;
    const int bid = (int)blockIdx.x;
    const int b = bid >> 3;
    const int s = bid & 7;

    // A[jt][kt]: exp(trans[i][j]) at row j = jt*16+m, k = i = kt*16+g*4+e
    // (identical construction to the round-4 kernel, HW-validated)
    b16x4 A[3][3];
#pragma unroll
    for (int jt = 0; jt < 3; ++jt) {
#pragma unroll
        for (int kt = 0; kt < 3; ++kt) {
            const int j = jt*16 + m;
            const float e0 = __expf(trans[(kt*16 + g*4 + 0)*NT + j]);
            const float e1 = __expf(trans[(kt*16 + g*4 + 1)*NT + j]);
            const float e2 = __expf(trans[(kt*16 + g*4 + 2)*NT + j]);
            const float e3 = __expf(trans[(kt*16 + g*4 + 3)*NT + j]);
            union { b16x4 v; unsigned u[2]; } r;
            r.u[0] = pkbf16(e0, e1);
            r.u[1] = pkbf16(e2, e3);
            A[jt][kt] = r.v;
        }
    }

    // Q = I as bf16 B-fragments: element (k = kt*16+g*4+e, col = ct*16+m)
    b16x4 Bf[3][3];
    {
        unsigned lo = 0, hi = 0;
        if (m == g*4 + 0) lo |= 0x3F80u;
        if (m == g*4 + 1) lo |= 0x3F800000u;
        if (m == g*4 + 2) hi |= 0x3F80u;
        if (m == g*4 + 3) hi |= 0x3F800000u;
        union { b16x4 v; unsigned u[2]; } idf, zf;
        idf.u[0] = lo; idf.u[1] = hi;
        zf.u[0] = 0u;  zf.u[1] = 0u;
#pragma unroll
        for (int kt = 0; kt < 3; ++kt)
#pragma unroll
            for (int ct = 0; ct < 3; ++ct)
                Bf[kt][ct] = (kt == ct) ? idf.v : zf.v;
    }

    const float* fb = feats + (size_t)b * NL * NT;
    const int* mkb = mask + (size_t)b * NL;

    const int t0 = s * SEGLEN + (s == 0 ? 1 : 0);   // t=0 handled by phase-2 init
    const int t1 = s * SEGLEN + SEGLEN - 1;

    int es = 0;

    f32x4 E0 = *(const f32x4*)(fb + (size_t)t0*NT +  0 + g*4);
    f32x4 E1 = *(const f32x4*)(fb + (size_t)t0*NT + 16 + g*4);
    f32x4 E2 = *(const f32x4*)(fb + (size_t)t0*NT + 32 + g*4);
    int mk = mkb[t0];

    for (int t = t0; t <= t1; ++t) {
        const int tn = (t < t1) ? (t + 1) : t1;
        f32x4 N0 = *(const f32x4*)(fb + (size_t)tn*NT +  0 + g*4);
        f32x4 N1 = *(const f32x4*)(fb + (size_t)tn*NT + 16 + g*4);
        f32x4 N2 = *(const f32x4*)(fb + (size_t)tn*NT + 32 + g*4);
        const int mkn = mkb[tn];

        if (mk > 0) {   // wave-uniform branch; masked step == identity matrix
            f32x4 W[3];
            W[0].x = __expf(E0.x); W[0].y = __expf(E0.y); W[0].z = __expf(E0.z); W[0].w = __expf(E0.w);
            W[1].x = __expf(E1.x); W[1].y = __expf(E1.y); W[1].z = __expf(E1.z); W[1].w = __expf(E1.w);
            W[2].x = __expf(E2.x); W[2].y = __expf(E2.y); W[2].z = __expf(E2.z); W[2].w = __expf(E2.w);

            f32x4 D[3][3];
#pragma unroll
            for (int jt = 0; jt < 3; ++jt)
#pragma unroll
                for (int ct = 0; ct < 3; ++ct)
                    D[jt][ct] = (f32x4){0.f, 0.f, 0.f, 0.f};

#pragma unroll
            for (int kt = 0; kt < 3; ++kt)
#pragma unroll
                for (int jt = 0; jt < 3; ++jt)
#pragma unroll
                    for (int ct = 0; ct < 3; ++ct)
                        D[jt][ct] = MFMA16(A[jt][kt], Bf[kt][ct], D[jt][ct]);

#pragma unroll
            for (int jt = 0; jt < 3; ++jt)
#pragma unroll
                for (int ct = 0; ct < 3; ++ct)
                    D[jt][ct] *= W[jt];   // row scale: row = jt*16+g*4+r matches W[jt][r]

            if ((t & 3) == 3) {   // renorm: wave-uniform power-of-2 strip
                float mx = 0.f;
#pragma unroll
                for (int jt = 0; jt < 3; ++jt)
#pragma unroll
                    for (int ct = 0; ct < 3; ++ct)
                        mx = fmaxf(mx, vmax4(D[jt][ct]));
#pragma unroll
                for (int o = 1; o < 64; o <<= 1)
                    mx = fmaxf(mx, __shfl_xor(mx, o, 64));
                const int ebb = (__float_as_int(mx) >> 23) & 255;
                const float sc = __int_as_float((254 - ebb) << 23);
                es += ebb - 127;
#pragma unroll
                for (int jt = 0; jt < 3; ++jt)
#pragma unroll
                    for (int ct = 0; ct < 3; ++ct)
                        D[jt][ct] *= sc;
            }

#pragma unroll
            for (int jt = 0; jt < 3; ++jt)
#pragma unroll
                for (int ct = 0; ct < 3; ++ct)
                    Bf[jt][ct] = packV(D[jt][ct]);   // D rows -> next B's k: in-lane
        }
        E0 = N0; E1 = N1; E2 = N2;
        mk = mkn;
    }

    // Final renorm + store row-major [48][48] bf16
    float Vf[3][3][4];
    float mx = 0.f;
#pragma unroll
    for (int kt = 0; kt < 3; ++kt)
#pragma unroll
        for (int ct = 0; ct < 3; ++ct) {
            union { b16x4 v; unsigned u[2]; } bb; bb.v = Bf[kt][ct];
            Vf[kt][ct][0] = bf16lo(bb.u[0]);
            Vf[kt][ct][1] = bf16hi(bb.u[0]);
            Vf[kt][ct][2] = bf16lo(bb.u[1]);
            Vf[kt][ct][3] = bf16hi(bb.u[1]);
            mx = fmaxf(mx, fmaxf(fmaxf(Vf[kt][ct][0], Vf[kt][ct][1]),
                                 fmaxf(Vf[kt][ct][2], Vf[kt][ct][3])));
        }
#pragma unroll
    for (int o = 1; o < 64; o <<= 1)
        mx = fmaxf(mx, __shfl_xor(mx, o, 64));
    const int ebb = (__float_as_int(mx) >> 23) & 255;
    const float sc = __int_as_float((254 - ebb) << 23);
    es += ebb - 127;

    unsigned short* qb = qws + (size_t)(b * NSEG + s) * (NT * NT);
#pragma unroll
    for (int kt = 0; kt < 3; ++kt)
#pragma unroll
        for (int ct = 0; ct < 3; ++ct)
#pragma unroll
            for (int e = 0; e < 4; ++e) {
                const int row = kt*16 + g*4 + e;
                const int col = ct*16 + m;
                const float v = Vf[kt][ct][e] * sc;   // pow2 scale: bf16-exact
                qb[row*NT + col] = (unsigned short)(__float_as_uint(v) >> 16);
            }
    if (lane == 0) esws[b * NSEG + s] = es;
}

// ---------------- Phase 2: per-batch combine (8 matvecs) + gold score ----------------
__global__ void __launch_bounds__(64) crf_phase2(
    const float* __restrict__ feats,
    const float* __restrict__ trans,
    const int* __restrict__ tags,
    const int* __restrict__ mask,
    const unsigned short* __restrict__ qws,
    const int* __restrict__ esws,
    float* __restrict__ out)
{
    const int b = (int)blockIdx.x;
    const int lane = (int)threadIdx.x;

    const float* fb = feats + (size_t)b * NL * NT;
    const int* tg = tags + (size_t)b * NL;
    const int* mk = mask + (size_t)b * NL;

    // gold path score, lane-parallel over time
    float gold = 0.f;
#pragma unroll 4
    for (int it = 0; it < NL/64; ++it) {
        const int t = it*64 + lane;
        const int tt = tg[t];
        if (mk[t] > 0) {
            gold += fb[(size_t)t*NT + tt];
            if (t > 0) gold += trans[tg[t-1]*NT + tt];
        }
    }

    __shared__ float vb[64];
    float v = (lane < NT) ? __expf(fb[lane]) : 0.f;   // alphaV_0 = exp(f[0])
    float esum = 0.f;

    for (int s = 0; s < NSEG; ++s) {
        __syncthreads();
        vb[lane] = v;
        __syncthreads();
        float acc = 0.f;
        if (lane < NT) {
            const unsigned short* Q = qws + (size_t)(b*NSEG + s)*(NT*NT) + lane*NT;
#pragma unroll
            for (int k8 = 0; k8 < 6; ++k8) {
                const uint4 q4 = *(const uint4*)(Q + k8*8);
                const float* vv = vb + k8*8;
                acc = fmaf(bf16lo(q4.x), vv[0], acc);
                acc = fmaf(bf16hi(q4.x), vv[1], acc);
                acc = fmaf(bf16lo(q4.y), vv[2], acc);
                acc = fmaf(bf16hi(q4.y), vv[3], acc);
                acc = fmaf(bf16lo(q4.z), vv[4], acc);
                acc = fmaf(bf16hi(q4.z), vv[5], acc);
                acc = fmaf(bf16lo(q4.w), vv[6], acc);
                acc = fmaf(bf16hi(q4.w), vv[7], acc);
            }
        }
        esum += (float)esws[b*NSEG + s];
        float mx = acc;
#pragma unroll
        for (int o = 1; o < 64; o <<= 1)
            mx = fmaxf(mx, __shfl_xor(mx, o, 64));
        const int ebb = (__float_as_int(mx) >> 23) & 255;
        const float sc = __int_as_float((254 - ebb) << 23);
        esum += (float)(ebb - 127);
        v = acc * sc;
    }

    float sv = v;
    float gg = gold;
#pragma unroll
    for (int o = 1; o < 64; o <<= 1) {
        sv += __shfl_xor(sv, o, 64);
        gg += __shfl_xor(gg, o, 64);
    }
    if (lane == 0) out[b] = esum * LN2F + __logf(sv) - gg;
}

// ---------------- Fallback: round-4 single-kernel (16 chains/wave) ----------------
// Used only if ws_size is too small for the scan workspace. Known-passing @290us.
#define STEP(kk, F, cc) do {                                                    \
    f32x4 W0, W1, W2;                                                           \
    W0.x = __expf(EB[0][kk].x); W0.y = __expf(EB[0][kk].y);                     \
    W0.z = __expf(EB[0][kk].z); W0.w = __expf(EB[0][kk].w);                     \
    W1.x = __expf(EB[1][kk].x); W1.y = __expf(EB[1][kk].y);                     \
    W1.z = __expf(EB[1][kk].z); W1.w = __expf(EB[1][kk].w);                     \
    W2.x = __expf(EB[2][kk].x); W2.y = __expf(EB[2][kk].y);                     \
    W2.z = __expf(EB[2][kk].z); W2.w = __expf(EB[2][kk].w);                     \
    {                                                                           \
        const int tn = ((((cc)+1) < NCH) ? ((cc)+1) : (cc)) * CH + (kk);        \
        EB[0][kk] = *(const f32x4*)(fb + (size_t)tn*NT +  0 + g*4);             \
        EB[1][kk] = *(const f32x4*)(fb + (size_t)tn*NT + 16 + g*4);             \
        EB[2][kk] = *(const f32x4*)(fb + (size_t)tn*NT + 32 + g*4);             \
    }                                                                           \
    if ((F) && (kk) == 0) {                                                     \
        V[0] = W0; V[1] = W1; V[2] = W2;                                        \
    } else {                                                                    \
        const f32x4 z = {0.f, 0.f, 0.f, 0.f};                                   \
        f32x4 d0 = MFMA16(A[0][0], Bf[0], z);                                   \
        f32x4 d1 = MFMA16(A[1][0], Bf[0], z);                                   \
        f32x4 d2 = MFMA16(A[2][0], Bf[0], z);                                   \
        d0 = MFMA16(A[0][1], Bf[1], d0);                                        \
        d1 = MFMA16(A[1][1], Bf[1], d1);                                        \
        d2 = MFMA16(A[2][1], Bf[1], d2);                                        \
        d0 = MFMA16(A[0][2], Bf[2], d0);                                        \
        d1 = MFMA16(A[1][2], Bf[2], d1);                                        \
        d2 = MFMA16(A[2][2], Bf[2], d2);                                        \
        const bool mk_ = mkc[kk] > 0;                                           \
        V[0] = mk_ ? d0 * W0 : V[0];                                            \
        V[1] = mk_ ? d1 * W1 : V[1];                                            \
        V[2] = mk_ ? d2 * W2 : V[2];                                            \
    }                                                                           \
    if (((kk) & 3) == 3) {                                                      \
        float mx = fmaxf(fmaxf(vmax4(V[0]), vmax4(V[1])), vmax4(V[2]));         \
        mx = fmaxf(mx, __shfl_xor(mx, 16, 64));                                 \
        mx = fmaxf(mx, __shfl_xor(mx, 32, 64));                                 \
        const int eb_ = (__float_as_int(mx) >> 23) & 255;                       \
        const float sc_ = __int_as_float((254 - eb_) << 23);                    \
        es += eb_ - 127;                                                        \
        V[0] *= sc_; V[1] *= sc_; V[2] *= sc_;                                  \
    }                                                                           \
    Bf[0] = packV(V[0]); Bf[1] = packV(V[1]); Bf[2] = packV(V[2]);              \
} while (0)

#define CHUNK(F, cc) do {                                                       \
    {                                                                           \
        const int ccn = (((cc)+1) < NCH) ? ((cc)+1) : (cc);                     \
        int4 a_ = *(const int4*)(tgP + ccn*CH);                                 \
        int4 b_ = *(const int4*)(tgP + ccn*CH + 4);                             \
        tgn[0]=a_.x; tgn[1]=a_.y; tgn[2]=a_.z; tgn[3]=a_.w;                     \
        tgn[4]=b_.x; tgn[5]=b_.y; tgn[6]=b_.z; tgn[7]=b_.w;                     \
        int4 c_ = *(const int4*)(mkP + ccn*CH);                                 \
        int4 d_ = *(const int4*)(mkP + ccn*CH + 4);                             \
        mkn[0]=c_.x; mkn[1]=c_.y; mkn[2]=c_.z; mkn[3]=c_.w;                     \
        mkn[4]=d_.x; mkn[5]=d_.y; mkn[6]=d_.z; mkn[7]=d_.w;                     \
    }                                                                           \
    float gtr[CH], gem[CH];                                                     \
    if (lane < 16) {                                                            \
        int pv_ = tp;                                                           \
        _Pragma("unroll")                                                       \
        for (int k = 0; k < CH; ++k) {                                          \
            const int cur_ = tgc[k];                                            \
            gtr[k] = trans[pv_*NT + cur_];                                      \
            gem[k] = fb[(size_t)((cc)*CH + k)*NT + cur_];                       \
            pv_ = cur_;                                                         \
        }                                                                       \
    }                                                                           \
    tp = tgc[CH-1];                                                             \
    STEP(0,F,cc); STEP(1,F,cc); STEP(2,F,cc); STEP(3,F,cc);                     \
    STEP(4,F,cc); STEP(5,F,cc); STEP(6,F,cc); STEP(7,F,cc);                     \
    if (lane < 16) {                                                            \
        _Pragma("unroll")                                                       \
        for (int k = 0; k < CH; ++k) {                                          \
            if (mkc[k] > 0) {                                                   \
                gE += gem[k];                                                   \
                if (!((F) && k == 0)) gT += gtr[k];                             \
            }                                                                   \
        }                                                                       \
    }                                                                           \
    _Pragma("unroll")                                                           \
    for (int k = 0; k < CH; ++k) { tgc[k] = tgn[k]; mkc[k] = mkn[k]; }          \
} while (0)

__global__ void __launch_bounds__(64, 1) crf_nll_fallback(
    const float* __restrict__ feats,
    const float* __restrict__ trans,
    const int* __restrict__ tags,
    const int* __restrict__ mask,
    float* __restrict__ out)
{
    const int lane = (int)threadIdx.x;
    const int m = lane & 15;
    const int g = lane >> 4;
    const int b0 = (int)blockIdx.x * 16;

    b16x4 A[3][3];
#pragma unroll
    for (int jt = 0; jt < 3; ++jt) {
#pragma unroll
        for (int kc = 0; kc < 3; ++kc) {
            const int j = jt*16 + m;
            const float e0 = __expf(trans[(kc*16 + g*4 + 0)*NT + j]);
            const float e1 = __expf(trans[(kc*16 + g*4 + 1)*NT + j]);
            const float e2 = __expf(trans[(kc*16 + g*4 + 2)*NT + j]);
            const float e3 = __expf(trans[(kc*16 + g*4 + 3)*NT + j]);
            union { b16x4 b; unsigned u[2]; } r;
            r.u[0] = pkbf16(e0, e1);
            r.u[1] = pkbf16(e2, e3);
            A[jt][kc] = r.b;
        }
    }

    const float* fb = feats + (size_t)(b0 + m) * NL * NT;
    const int* tgP = tags + (size_t)(b0 + m) * NL;
    const int* mkP = mask + (size_t)(b0 + m) * NL;

    f32x4 EB[3][CH];
#pragma unroll
    for (int k = 0; k < CH; ++k) {
#pragma unroll
        for (int jt = 0; jt < 3; ++jt)
            EB[jt][k] = *(const f32x4*)(fb + (size_t)k*NT + jt*16 + g*4);
    }

    int tgc[CH], mkc[CH], tgn[CH], mkn[CH];
    {
        int4 a_ = *(const int4*)(tgP);
        int4 b_ = *(const int4*)(tgP + 4);
        tgc[0]=a_.x; tgc[1]=a_.y; tgc[2]=a_.z; tgc[3]=a_.w;
        tgc[4]=b_.x; tgc[5]=b_.y; tgc[6]=b_.z; tgc[7]=b_.w;
        int4 c_ = *(const int4*)(mkP);
        int4 d_ = *(const int4*)(mkP + 4);
        mkc[0]=c_.x; mkc[1]=c_.y; mkc[2]=c_.z; mkc[3]=c_.w;
        mkc[4]=d_.x; mkc[5]=d_.y; mkc[6]=d_.z; mkc[7]=d_.w;
    }

    f32x4 V[3];
    b16x4 Bf[3];
    int es = 0;
    float gT = 0.f, gE = 0.f;
    int tp = 0;

    CHUNK(1, 0);
    for (int cc = 1; cc < NCH; ++cc) {
        CHUNK(0, cc);
    }

    float s = ((V[0].x + V[0].y) + (V[0].z + V[0].w))
            + ((V[1].x + V[1].y) + (V[1].z + V[1].w))
            + ((V[2].x + V[2].y) + (V[2].z + V[2].w));
    s += __shfl_xor(s, 16, 64);
    s += __shfl_xor(s, 32, 64);

    const float res = (float)es * LN2F + __logf(s) - gT - gE;
    if (lane < 16) out[b0 + lane] = res;
}

extern "C" void kernel_launch(void* const* d_in, const int* in_sizes, int n_in,
                              void* d_out, int out_size, void* d_ws, size_t ws_size,
                              hipStream_t stream) {
    const float* feats = (const float*)d_in[0];
    const float* trans = (const float*)d_in[1];
    const int*   tags  = (const int*)d_in[2];
    const int*   mask  = (const int*)d_in[3];
    float* out = (float*)d_out;

    const size_t qbytes = (size_t)NB * NSEG * NT * NT * sizeof(unsigned short);
    const size_t need = qbytes + (size_t)NB * NSEG * sizeof(int);

    if (ws_size >= need) {
        unsigned short* qws = (unsigned short*)d_ws;
        int* esws = (int*)((char*)d_ws + qbytes);
        crf_phase1<<<dim3(NB*NSEG), dim3(64), 0, stream>>>(feats, trans, mask, qws, esws);
        crf_phase2<<<dim3(NB), dim3(64), 0, stream>>>(feats, trans, tags, mask, qws, esws, out);
    } else {
        crf_nll_fallback<<<dim3(NB/16), dim3(64), 0, stream>>>(feats, trans, tags, mask, out);
    }
}